// Round 17
// baseline (7337.205 us; speedup 1.0000x reference)
//
#include <hip/hip_runtime.h>
#include <hip/hip_fp16.h>

#define T_STEPS 2048
#define B_SZ 128
#define I_SZ 10
#define H_SZ 512

#define NGRP 8            // batch groups (16 rows each)
#define GWG 8             // wgs per group
#define NWG (NGRP * GWG)  // 64 workgroups
#define BSLICE 16         // batch rows per group
#define WCOL 64           // hidden cols per wg
#define NTHR 256          // 4 waves; 1 wave/SIMD -> up to 512 VGPR

typedef _Float16 f16x8 __attribute__((ext_vector_type(8)));
typedef float f32x4 __attribute__((ext_vector_type(4)));
typedef float f32x2 __attribute__((ext_vector_type(2)));
typedef unsigned u32x4 __attribute__((ext_vector_type(4)));
typedef unsigned u32x2 __attribute__((ext_vector_type(2)));
typedef unsigned long long u64t;

// Tagged h buffers: [2][NGRP][BSLICE][H/2] u64, u64 = (tag << 32) | 2xfp16.
// MUST be zeroed before every persistent launch (stale tags / 0xAA poison
// would satisfy the tag check).
__global__ void clear_hbuf_kernel(u64t* p) {
    const int i = blockIdx.x * 256 + threadIdx.x;   // 16384 threads
    #pragma unroll
    for (int k = 0; k < 4; ++k)
        __hip_atomic_store(p + i + k * 16384, 0ull,
                           __ATOMIC_RELAXED, __HIP_MEMORY_SCOPE_AGENT);
}

// Persistent LSTM, R13 sync machinery + IN-REGISTER gate update (no lds_g,
// no B2).
//
//   8 batch-groups x 8 wgs; wg = 4 waves x 64 threads. Wave w owns local
//   cols [w*16, w*16+16) and computes ALL FOUR gates for them (wf[4][16]
//   register-resident; 1 wave/SIMD, 512-VGPR budget). MFMA C-layout hands
//   each lane acc[gate][r] for (its col, 4 batch rows) -- the c/h update is
//   pure-register. Publish packs col-pairs via shfl_xor.
//
//   PUBLISH EXCHANGE (R16 bugfix): granule (row, cp) = {h[row][2cp],
//   h[row][2cp+1]}. Even fr_col lane stores rows 4k,4k+1 and needs the odd
//   lane's hst[j] for ROW 4k+j; so in iteration j the even lane CONTRIBUTES
//   hst[2+j] (what the odd partner stores) and CONSUMES the received hst[j].
//   R15 had both lanes contribute hst[own r] -> odd columns row-permuted.
//   Ternary VALUE selects keep all register indices static (no scratch).
//
//   publish: tagged u64 fire-and-forget (relaxed agent = sc0 sc1).
//   consume: wave0 spins on 8 sentinel granules -> spinB -> ONE coalesced
//   sweep (1KB contiguous per instruction) with per-granule tag validation
//   (stale granules re-read exec-masked; correctness rests on tags only).
//   global_load imm offset is 13-bit SIGNED -> two base pointers.
//
// Double-buffer safety (R9/R10/R13 proof): publish at end of step s writes
// tag s+2 into buf[(s+1)&1]; overwriting buf[p] again requires all wgs to
// have passed staging(t) of buf[p], enforced by the tag chain.
// LDS WAR: sweep-writes(t+1) happen after spinB(t+1); all h_stage MFMA
// reads(t) precede spinB(t+1) in program order. 2 barriers/step total.
__global__ __launch_bounds__(NTHR, 1) void lstm_persistent(
    const float* __restrict__ x,     // [T,B,I]
    const float* __restrict__ hx,    // [B,H]
    const float* __restrict__ cx,    // [B,H]
    const float* __restrict__ W_ih,  // [4H,I]
    const float* __restrict__ W_hh,  // [4H,H]
    const float* __restrict__ b_ih,  // [4H]
    const float* __restrict__ b_hh,  // [4H]
    float* __restrict__ out,         // [3*B*H] = h, h, c
    u64t* hbuf)                      // [2][NGRP][BSLICE][H/2] tagged
{
    __shared__ _Float16 h_stage[BSLICE][520];   // row stride 1040B

    const int wg   = blockIdx.x;
    const int g    = wg >> 3;          // batch group 0..7
    const int wgin = wg & 7;           // wg within group 0..7
    const int tid  = threadIdx.x;
    const int wid  = tid >> 6;         // wave 0..3
    const int lane = tid & 63;
    const int fr_col = lane & 15;      // col within 16-col fragment
    const int fr_kg  = lane >> 4;      // 0..3 (k-group / row-group)

    const int colL = wid * 16 + fr_col;          // local col 0..63
    const int gcol = wgin * WCOL + colL;         // global hidden col

    // ---- W_hh B-fragments: 4 gates x 16 K-chunks, fp16 register-resident
    f16x8 wf[4][16];
    #pragma unroll
    for (int gt = 0; gt < 4; ++gt)
        #pragma unroll
        for (int c = 0; c < 16; ++c) {
            const float* p = W_hh + (size_t)(gt * H_SZ + gcol) * H_SZ + c * 32 + fr_kg * 8;
            f16x8 w;
            #pragma unroll
            for (int e = 0; e < 8; ++e) w[e] = (_Float16)p[e];
            wf[gt][c] = w;
        }

    // ---- W_ih rows + combined bias (4 gates, this col)
    float wih[4][I_SZ], bias[4];
    #pragma unroll
    for (int gt = 0; gt < 4; ++gt) {
        #pragma unroll
        for (int i = 0; i < I_SZ; ++i) wih[gt][i] = W_ih[(gt * H_SZ + gcol) * I_SZ + i];
        bias[gt] = b_ih[gt * H_SZ + gcol] + b_hh[gt * H_SZ + gcol];
    }

    // ---- owned cells: 4 rows x 1 col per thread (rows fr_kg*4..+3)
    float cst[4], hst[4];
    #pragma unroll
    for (int r = 0; r < 4; ++r) {
        const int gbrow = g * BSLICE + fr_kg * 4 + r;
        cst[r] = cx[gbrow * H_SZ + gcol];
        hst[r] = hx[gbrow * H_SZ + gcol];
    }

    // ---- publish geometry: granule (row, colpair). Even fr_col lane stores
    //      rows 4k,4k+1; odd stores 4k+2,4k+3.
    const int cp = wgin * 32 + wid * 8 + (fr_col >> 1);     // colpair 0..255
    const bool odd = (fr_col & 1);
    const int prow0 = fr_kg * 4 + (odd ? 2 : 0);            // first of 2 rows

    // ---- sentinel for producer wg p = granule (row 15, last colpair of p)
    const int sent_idx = 15 * 256 + (lane & 7) * 32 + 31;

    // ---- publish h(0) with tag 1 into buffer 0 (corrected exchange)
    {
        u64t* hb0 = hbuf + (size_t)g * (BSLICE * 256);
        #pragma unroll
        for (int j = 0; j < 2; ++j) {
            const float give = odd ? hst[j] : hst[2 + j];   // partner's row value
            const float hp   = __shfl_xor(give, 1);         // value for MY row
            const float own  = odd ? hst[2 + j] : hst[j];
            const float lo = odd ? hp : own;
            const float hi = odd ? own : hp;
            union { _Float16 f[2]; unsigned u; } pk;
            pk.f[0] = (_Float16)lo; pk.f[1] = (_Float16)hi;
            __hip_atomic_store(hb0 + (size_t)(prow0 + j) * 256 + cp,
                               ((u64t)1u << 32) | pk.u,
                               __ATOMIC_RELAXED, __HIP_MEMORY_SCOPE_AGENT);
        }
    }

    #pragma unroll 1
    for (int t = 0; t < T_STEPS; ++t) {
        // -- x_t @ W_ih^T + bias, all 4 gates (h-independent; overlaps
        //    sentinel landing)
        f32x4 acc[4];
        #pragma unroll
        for (int r = 0; r < 4; ++r) {
            const int grow = g * BSLICE + fr_kg * 4 + r;
            const f32x2* xp = (const f32x2*)(x + ((size_t)t * B_SZ + grow) * I_SZ);
            const f32x2 a0 = xp[0], a1 = xp[1], a2 = xp[2], a3 = xp[3], a4 = xp[4];
            #pragma unroll
            for (int gt = 0; gt < 4; ++gt) {
                float s = bias[gt];
                s += a0.x*wih[gt][0] + a0.y*wih[gt][1] + a1.x*wih[gt][2] + a1.y*wih[gt][3]
                   + a2.x*wih[gt][4] + a2.y*wih[gt][5] + a3.x*wih[gt][6] + a3.y*wih[gt][7]
                   + a4.x*wih[gt][8] + a4.y*wih[gt][9];
                acc[gt][r] = s;
            }
        }

        const u64t* hb = hbuf + ((size_t)(t & 1) * NGRP + g) * (BSLICE * 256);
        const unsigned tgt = (unsigned)(t + 1);

        // -- sentinel spin: wave0 only (8 granules, 8B/lane/retry)
        if (wid == 0) {
            const u64t* sp = hb + sent_idx;
            for (;;) {
                u64t sv = __hip_atomic_load(sp, __ATOMIC_RELAXED,
                                            __HIP_MEMORY_SCOPE_AGENT);
                if (__all((unsigned)(sv >> 32) >= tgt)) break;
                __builtin_amdgcn_s_sleep(1);
            }
        }
        __syncthreads();   // spinB: sentinels fresh; also fences h_stage WAR

        // -- ONE coalesced tagged sweep: wave stages 8KB (8 x 1KB contiguous);
        //    two base pointers (13-bit signed offset limit), offsets 0..3072.
        {
            const char* spA = (const char*)hb + wid * 8192 + lane * 16;
            const char* spB = spA + 4096;
            u32x4 q0, q1, q2, q3, q4, q5, q6, q7;
            bool done = false;
            for (;;) {
                if (!done) {
                    asm volatile(
                        "global_load_dwordx4 %0, %8, off sc0 sc1\n\t"
                        "global_load_dwordx4 %1, %8, off offset:1024 sc0 sc1\n\t"
                        "global_load_dwordx4 %2, %8, off offset:2048 sc0 sc1\n\t"
                        "global_load_dwordx4 %3, %8, off offset:3072 sc0 sc1\n\t"
                        "global_load_dwordx4 %4, %9, off sc0 sc1\n\t"
                        "global_load_dwordx4 %5, %9, off offset:1024 sc0 sc1\n\t"
                        "global_load_dwordx4 %6, %9, off offset:2048 sc0 sc1\n\t"
                        "global_load_dwordx4 %7, %9, off offset:3072 sc0 sc1\n\t"
                        "s_waitcnt vmcnt(0)"
                        : "=&v"(q0), "=&v"(q1), "=&v"(q2), "=&v"(q3),
                          "=&v"(q4), "=&v"(q5), "=&v"(q6), "=&v"(q7)
                        : "v"(spA), "v"(spB) : "memory");
                    done = (q0.y >= tgt && q0.w >= tgt) && (q1.y >= tgt && q1.w >= tgt) &&
                           (q2.y >= tgt && q2.w >= tgt) && (q3.y >= tgt && q3.w >= tgt) &&
                           (q4.y >= tgt && q4.w >= tgt) && (q5.y >= tgt && q5.w >= tgt) &&
                           (q6.y >= tgt && q6.w >= tgt) && (q7.y >= tgt && q7.w >= tgt);
                }
                if (__all(done)) break;
                __builtin_amdgcn_s_sleep(1);
            }
            // de-tag -> LDS. granule q = wid*1024 + m*128 + lane*2 (+1):
            // row = q>>8, colpair = q&255.
            const int qb = wid * 1024 + lane * 2;
            #pragma unroll
            for (int m = 0; m < 8; ++m) {
                const int q = qb + m * 128;
                const int row = q >> 8, p = q & 255;
                u32x4 qq;
                switch (m) {   // static selection (unrolled)
                    case 0: qq = q0; break; case 1: qq = q1; break;
                    case 2: qq = q2; break; case 3: qq = q3; break;
                    case 4: qq = q4; break; case 5: qq = q5; break;
                    case 6: qq = q6; break; default: qq = q7; break;
                }
                *(u32x2*)&h_stage[row][p * 2] = (u32x2){qq.x, qq.z};
            }
        }
        __syncthreads();   // B1: staging visible

        // -- 16 K-chunks x 4 gates = 64 MFMAs (4 independent acc chains)
        #pragma unroll
        for (int c = 0; c < 16; ++c) {
            const f16x8 a = *(const f16x8*)&h_stage[fr_col][c * 32 + fr_kg * 8];
            #pragma unroll
            for (int gt = 0; gt < 4; ++gt)
                acc[gt] = __builtin_amdgcn_mfma_f32_16x16x32_f16(a, wf[gt][c], acc[gt], 0, 0, 0);
        }

        // -- IN-REGISTER c/h update for 4 owned cells (no LDS exchange)
        #pragma unroll
        for (int r = 0; r < 4; ++r) {
            const float ig = 1.f / (1.f + __expf(-acc[0][r]));
            const float fg = 1.f / (1.f + __expf(-acc[1][r]));
            const float eg = __expf(-2.f * acc[2][r]);
            const float tg = (1.f - eg) / (1.f + eg);
            const float og = 1.f / (1.f + __expf(-acc[3][r]));
            cst[r] = fg * cst[r] + ig * tg;
            const float ec = __expf(-2.f * cst[r]);
            hst[r] = og * (1.f - ec) / (1.f + ec);
        }

        // -- publish tagged h(t+1): corrected shfl col-pairing
        if (t < T_STEPS - 1) {
            u64t* hbn = hbuf + ((size_t)((t + 1) & 1) * NGRP + g) * (BSLICE * 256);
            const u64t tagw = (u64t)(unsigned)(t + 2) << 32;
            #pragma unroll
            for (int j = 0; j < 2; ++j) {
                const float give = odd ? hst[j] : hst[2 + j];   // partner's row value
                const float hp   = __shfl_xor(give, 1);         // value for MY row
                const float own  = odd ? hst[2 + j] : hst[j];
                const float lo = odd ? hp : own;
                const float hi = odd ? own : hp;
                union { _Float16 f[2]; unsigned u; } pk;
                pk.f[0] = (_Float16)lo; pk.f[1] = (_Float16)hi;
                __hip_atomic_store(hbn + (size_t)(prow0 + j) * 256 + cp,
                                   tagw | pk.u,
                                   __ATOMIC_RELAXED, __HIP_MEMORY_SCOPE_AGENT);
            }
        }
    }

    // ---- outputs: (h, h, c), each [B,H] f32; 4 cells per thread
    #pragma unroll
    for (int r = 0; r < 4; ++r) {
        const int gbrow = g * BSLICE + fr_kg * 4 + r;
        out[gbrow * H_SZ + gcol]                   = hst[r];
        out[B_SZ * H_SZ + gbrow * H_SZ + gcol]     = hst[r];
        out[2 * B_SZ * H_SZ + gbrow * H_SZ + gcol] = cst[r];
    }
}

extern "C" void kernel_launch(void* const* d_in, const int* in_sizes, int n_in,
                              void* d_out, int out_size, void* d_ws, size_t ws_size,
                              hipStream_t stream) {
    const float* x    = (const float*)d_in[0];
    const float* hx   = (const float*)d_in[1];
    const float* cx   = (const float*)d_in[2];
    const float* W_ih = (const float*)d_in[3];
    const float* W_hh = (const float*)d_in[4];
    const float* b_ih = (const float*)d_in[5];
    const float* b_hh = (const float*)d_in[6];
    float* out = (float*)d_out;

    // ws: [0, 512KB) tagged h double-buffer
    u64t* hbuf = (u64t*)d_ws;

    clear_hbuf_kernel<<<64, 256, 0, stream>>>(hbuf);
    lstm_persistent<<<NWG, NTHR, 0, stream>>>(x, hx, cx, W_ih, W_hh, b_ih, b_hh,
                                              out, hbuf);
}